// Round 1
// baseline (450.304 us; speedup 1.0000x reference)
//
#include <hip/hip_runtime.h>
#include <math.h>

#define BATCH 4
#define NCH 4
#define H 160
#define W 160
#define NPIX (H * W)          // 25600
#define PRE_K 2048
#define TOPK 500
#define PROB_T 0.75f
#define IOU_T 0.5f
#define COV 10.0f

// ---- workspace layout (bytes) ----
#define SCORE_OFF 0u                 // float [B][NPIX]
#define FS_OFF    409600u            // float [B][NPIX]  frontal scores (raster order)
#define FIDX_OFF  819200u            // int   [B][NPIX]  frontal pixel idx
#define F_OFF     1228800u           // int   [B]
#define CIDX_OFF  1228864u           // int   [B][PRE_K]
#define CSC_OFF   1261632u           // float [B][PRE_K]
#define CBOX_OFF  1294400u           // float [B][PRE_K][4]
#define SUP_OFF   1425472u           // u64   [B][32][PRE_K]  (word-transposed)
#define KEEP_OFF  3522624u           // u64   [B][32]
#define NV_OFF    3523648u           // int   [B]
#define PAR_OFF   3523712u           // float [B][TOPK][5]  (muy,mux,dy,dx,p)

// out layout (floats)
#define OUT_HEAT_OFF 0
#define OUT_MASK_OFF 102400
#define OUT_BOX_OFF  512000
#define OUT_VAL_OFF  520000

typedef unsigned long long u64;

// -------- block exclusive scan over 256 ints --------
__device__ __forceinline__ int block_scan_excl(int v, int tid, int* tmp, int* total) {
    tmp[tid] = v;
    __syncthreads();
    for (int off = 1; off < 256; off <<= 1) {
        int y = (tid >= off) ? tmp[tid - off] : 0;
        __syncthreads();
        tmp[tid] += y;
        __syncthreads();
    }
    int incl = tmp[tid];
    *total = tmp[255];
    __syncthreads();
    return incl - v;
}

// K1: per-pixel softmax-max / argmax / score
__global__ void k_score(const float* __restrict__ mask, float* __restrict__ score) {
    int b = blockIdx.y;
    int pix = blockIdx.x * 256 + threadIdx.x;
    const float* mp = mask + (size_t)b * NCH * NPIX + pix;
    float x0 = mp[0], x1 = mp[NPIX], x2 = mp[2 * NPIX], x3 = mp[3 * NPIX];
    float m = x0; int c = 0;
    if (x1 > m) { m = x1; c = 1; }
    if (x2 > m) { m = x2; c = 2; }
    if (x3 > m) { m = x3; c = 3; }
    float sum = ((expf(x0 - m) + expf(x1 - m)) + expf(x2 - m)) + expf(x3 - m);
    float prob = 1.0f / sum;
    bool frontal = (c != 0) && (prob > PROB_T);
    score[(size_t)b * NPIX + pix] = frontal ? prob : -1.0f;
}

// K2: ordered compaction (one block per image).
// Pass 1: frontal pixels (raster order) -> flist, F. Pass 2: first (PRE_K - F)
// non-frontal pixels fill cand slots F..PRE_K-1 with score -1 (stable top_k padding).
__global__ void k_compact(const float* __restrict__ score, float* __restrict__ fs,
                          int* __restrict__ fidx, int* __restrict__ Fout,
                          int* __restrict__ cand_idx, float* __restrict__ cand_score) {
    int b = blockIdx.x;
    int tid = threadIdx.x;
    __shared__ int tmp[256];
    __shared__ int s_off;
    const float* sc = score + (size_t)b * NPIX;
    if (tid == 0) s_off = 0;
    __syncthreads();
    for (int base = 0; base < NPIX; base += 256) {
        int i = base + tid;
        float s = sc[i];
        int fl = (s > 0.0f) ? 1 : 0;
        int tot;
        int pre = block_scan_excl(fl, tid, tmp, &tot);
        if (fl) {
            int p = s_off + pre;
            fs[(size_t)b * NPIX + p] = s;
            fidx[(size_t)b * NPIX + p] = i;
        }
        __syncthreads();
        if (tid == 0) s_off += tot;
        __syncthreads();
    }
    int F = s_off;
    if (tid == 0) Fout[b] = F;
    __syncthreads();
    if (F < PRE_K) {
        if (tid == 0) s_off = 0;
        __syncthreads();
        for (int base = 0; base < NPIX; base += 256) {
            int i = base + tid;
            float s = sc[i];
            int nf = (s > 0.0f) ? 0 : 1;
            int tot;
            int pre = block_scan_excl(nf, tid, tmp, &tot);
            int slot = F + s_off + pre;
            if (nf && slot < PRE_K) {
                cand_idx[(size_t)b * PRE_K + slot] = i;
                cand_score[(size_t)b * PRE_K + slot] = -1.0f;
            }
            __syncthreads();
            if (tid == 0) s_off += tot;
            __syncthreads();
            if (F + s_off >= PRE_K) break;
        }
    }
}

// K3: exact rank of each frontal element (JAX top_k semantics: desc value, ties -> lower idx)
__global__ void k_rank(const float* __restrict__ fs, const int* __restrict__ fidx,
                       const int* __restrict__ Fout, int* __restrict__ cand_idx,
                       float* __restrict__ cand_score) {
    int b = blockIdx.y;
    int F = Fout[b];
    if (blockIdx.x * 256 >= F) return;
    int i = blockIdx.x * 256 + threadIdx.x;
    bool act = i < F;
    float si = 0.0f; int xi = 0;
    if (act) { si = fs[(size_t)b * NPIX + i]; xi = fidx[(size_t)b * NPIX + i]; }
    int rank = 0;
    __shared__ float ls[256];
    __shared__ int li[256];
    for (int base = 0; base < F; base += 256) {
        int j = base + threadIdx.x;
        if (j < F) { ls[threadIdx.x] = fs[(size_t)b * NPIX + j]; li[threadIdx.x] = fidx[(size_t)b * NPIX + j]; }
        __syncthreads();
        int lim = min(256, F - base);
        if (act) {
            for (int k = 0; k < lim; ++k) {
                float sj = ls[k]; int xj = li[k];
                rank += (sj > si || (sj == si && xj < xi)) ? 1 : 0;
            }
        }
        __syncthreads();
    }
    if (act && rank < PRE_K) {
        cand_idx[(size_t)b * PRE_K + rank] = xi;
        cand_score[(size_t)b * PRE_K + rank] = si;
    }
}

// K4: build candidate boxes (y,x,y,x) + bias
__global__ void k_boxes(const float* __restrict__ bias, const int* __restrict__ cand_idx,
                        float* __restrict__ cand_box) {
    int t = blockIdx.x * 256 + threadIdx.x;   // [0, BATCH*PRE_K)
    int b = t >> 11;
    int s = t & (PRE_K - 1);
    int pix = cand_idx[(size_t)b * PRE_K + s];
    float y = (float)(pix / W), x = (float)(pix % W);
    const float* bb = bias + (size_t)b * 4 * NPIX;
    float4 box;
    box.x = y + bb[0 * NPIX + pix];
    box.y = x + bb[1 * NPIX + pix];
    box.z = y + bb[2 * NPIX + pix];
    box.w = x + bb[3 * NPIX + pix];
    ((float4*)cand_box)[(size_t)b * PRE_K + s] = box;
}

// K5: suppression bitmatrix (bits only for j > i && iou > 0.5), stored transposed sup[b][w][i]
__global__ void k_iou(const float* __restrict__ cand_box, u64* __restrict__ sup) {
    int b = blockIdx.y;
    int r0 = blockIdx.x * 8;
    __shared__ float ly1[PRE_K], lx1[PRE_K], ly2[PRE_K], lx2[PRE_K], lar[PRE_K];
    for (int k = threadIdx.x; k < PRE_K; k += 256) {
        float4 v = ((const float4*)cand_box)[(size_t)b * PRE_K + k];
        ly1[k] = v.x; lx1[k] = v.y; ly2[k] = v.z; lx2[k] = v.w;
        lar[k] = (v.z - v.x) * (v.w - v.y);
    }
    __syncthreads();
    int lr = threadIdx.x >> 5;
    int w = threadIdx.x & 31;
    int i = r0 + lr;
    float ay1 = ly1[i], ax1 = lx1[i], ay2 = ly2[i], ax2 = lx2[i], aa = lar[i];
    u64 bits = 0;
    int jbase = w * 64;
    #pragma unroll 4
    for (int jj = 0; jj < 64; ++jj) {
        int jo = (jj + w) & 63;             // bank-conflict-free rotation
        int j = jbase + jo;
        if (j > i) {
            float lty = fmaxf(ay1, ly1[j]);
            float ltx = fmaxf(ax1, lx1[j]);
            float rby = fminf(ay2, ly2[j]);
            float rbx = fminf(ax2, lx2[j]);
            float wy = fmaxf(rby - lty, 0.0f);
            float wx = fmaxf(rbx - ltx, 0.0f);
            float inter = wy * wx;
            float iou = inter / ((aa + lar[j]) - inter);
            if (iou > IOU_T) bits |= (1ull << jo);
        }
    }
    sup[(size_t)b * 32 * PRE_K + (size_t)w * PRE_K + i] = bits;
}

// K6: serial greedy NMS, one wave per image. lane w owns keep word w (duplicated for lanes>=32).
__global__ void k_nms(const u64* __restrict__ sup, const int* __restrict__ Fout,
                      u64* __restrict__ keep) {
    int b = blockIdx.x;
    int lane = threadIdx.x;
    int w = lane & 31;
    int F = Fout[b];
    int V = F < PRE_K ? F : PRE_K;
    int lo = w * 64;
    int rem = V - lo;
    u64 kw = (rem >= 64) ? ~0ull : (rem <= 0 ? 0ull : ((1ull << rem) - 1ull));
    const u64* rowp = sup + (size_t)b * 32 * PRE_K + (size_t)w * PRE_K;
    u64 r[8], rn[8];
    if (V > 0) {
        #pragma unroll
        for (int k = 0; k < 8; ++k) r[k] = rowp[k];
        for (int i0 = 0; i0 < V; i0 += 8) {
            bool pf = (i0 + 8 < PRE_K);
            if (pf) {
                #pragma unroll
                for (int k = 0; k < 8; ++k) rn[k] = rowp[i0 + 8 + k];
            }
            #pragma unroll
            for (int k = 0; k < 8; ++k) {
                int ii = i0 + k;
                if (ii >= V) break;
                int ow = ii >> 6;
                u64 kb = __shfl(kw, ow);
                if ((kb >> (ii & 63)) & 1ull) kw &= ~r[k];
            }
            if (pf) {
                #pragma unroll
                for (int k = 0; k < 8; ++k) r[k] = rn[k];
            }
        }
    }
    if (lane < 32) keep[(size_t)b * 32 + w] = kw;
}

// K7: final top-500 (kept slots in order, then non-kept in slot order) + outputs + heat params
__global__ void k_finalize(const u64* __restrict__ keep, const float* __restrict__ cand_score,
                           const float* __restrict__ cand_box, float* __restrict__ out_boxes,
                           float* __restrict__ out_valid, float* __restrict__ params,
                           int* __restrict__ NV) {
    int b = blockIdx.x;
    int tid = threadIdx.x;
    __shared__ u64 kws[32];
    __shared__ int tmp[256];
    if (tid < 32) kws[tid] = keep[(size_t)b * 32 + tid];
    __syncthreads();
    int s0 = tid * 8;
    int bits8 = (int)((kws[s0 >> 6] >> (s0 & 63)) & 0xFFull);
    int cnt = __popc(bits8);
    int tot;
    int kpre = block_scan_excl(cnt, tid, tmp, &tot);
    int NK = tot;
    for (int k = 0; k < 8; ++k) {
        int s = s0 + k;
        int kept = (bits8 >> k) & 1;
        int pos = kept ? kpre : (NK + s - kpre);
        if (pos < TOPK) {
            float4 bx = ((const float4*)cand_box)[(size_t)b * PRE_K + s];
            ((float4*)out_boxes)[(size_t)b * TOPK + pos] = bx;
            out_valid[(size_t)b * TOPK + pos] = kept ? 1.0f : 0.0f;
            if (kept) {
                float scv = cand_score[(size_t)b * PRE_K + s];
                float* pp = params + ((size_t)b * TOPK + pos) * 5;
                pp[0] = (bx.x + bx.z) * 0.5f;   // muy
                pp[1] = (bx.y + bx.w) * 0.5f;   // mux
                pp[2] = (bx.z - bx.x) / COV;    // sigma_y / cov
                pp[3] = (bx.w - bx.y) / COV;    // sigma_x / cov
                pp[4] = scv;                    // prob
            }
        }
        kpre += kept;
    }
    if (tid == 0) NV[b] = NK < TOPK ? NK : TOPK;
}

// K8: heat map — max over valid boxes of exp(-0.5 |z|^2) * p  (invalid boxes contribute exactly 0)
__global__ void k_heat(const float* __restrict__ params, const int* __restrict__ NV,
                       float* __restrict__ heat) {
    int b = blockIdx.y;
    int pix = blockIdx.x * 256 + threadIdx.x;
    int nv = NV[b];
    __shared__ float lp[TOPK * 5];
    for (int k = threadIdx.x; k < nv * 5; k += 256) lp[k] = params[(size_t)b * TOPK * 5 + k];
    __syncthreads();
    float py = (float)(pix / W), px = (float)(pix % W);
    float m = 0.0f;
    for (int t = 0; t < nv; ++t) {
        float muy = lp[t * 5 + 0], mux = lp[t * 5 + 1];
        float dy = lp[t * 5 + 2], dx = lp[t * 5 + 3], p = lp[t * 5 + 4];
        float zy = (py - muy) / dy;
        float zx = (px - mux) / dx;
        float g = expf(-0.5f * (zy * zy + zx * zx)) * p;
        m = fmaxf(m, g);
    }
    heat[(size_t)b * NPIX + pix] = m;
}

extern "C" void kernel_launch(void* const* d_in, const int* in_sizes, int n_in,
                              void* d_out, int out_size, void* d_ws, size_t ws_size,
                              hipStream_t stream) {
    const float* mask = (const float*)d_in[0];
    const float* bias = (const float*)d_in[1];
    float* out = (float*)d_out;
    char* ws = (char*)d_ws;

    float* score      = (float*)(ws + SCORE_OFF);
    float* fs         = (float*)(ws + FS_OFF);
    int*   fidx       = (int*)(ws + FIDX_OFF);
    int*   Fout       = (int*)(ws + F_OFF);
    int*   cand_idx   = (int*)(ws + CIDX_OFF);
    float* cand_score = (float*)(ws + CSC_OFF);
    float* cand_box   = (float*)(ws + CBOX_OFF);
    u64*   sup        = (u64*)(ws + SUP_OFF);
    u64*   keep       = (u64*)(ws + KEEP_OFF);
    int*   NV         = (int*)(ws + NV_OFF);
    float* params     = (float*)(ws + PAR_OFF);

    // mask passthrough (output 1)
    hipMemcpyAsync(out + OUT_MASK_OFF, mask, (size_t)BATCH * NCH * NPIX * sizeof(float),
                   hipMemcpyDeviceToDevice, stream);

    dim3 g100(NPIX / 256, BATCH);
    k_score<<<g100, 256, 0, stream>>>(mask, score);
    k_compact<<<BATCH, 256, 0, stream>>>(score, fs, fidx, Fout, cand_idx, cand_score);
    k_rank<<<g100, 256, 0, stream>>>(fs, fidx, Fout, cand_idx, cand_score);
    k_boxes<<<dim3(BATCH * PRE_K / 256), 256, 0, stream>>>(bias, cand_idx, cand_box);
    k_iou<<<dim3(PRE_K / 8, BATCH), 256, 0, stream>>>(cand_box, sup);
    k_nms<<<BATCH, 64, 0, stream>>>(sup, Fout, keep);
    k_finalize<<<BATCH, 256, 0, stream>>>(keep, cand_score, cand_box,
                                          out + OUT_BOX_OFF, out + OUT_VAL_OFF, params, NV);
    k_heat<<<g100, 256, 0, stream>>>(params, NV, out + OUT_HEAT_OFF);
}

// Round 2
// 336.660 us; speedup vs baseline: 1.3376x; 1.3376x over previous
//
#include <hip/hip_runtime.h>
#include <math.h>

#define BATCH 4
#define NCH 4
#define H 160
#define W 160
#define NPIX (H * W)          // 25600
#define PRE_K 2048
#define TOPK 500
#define PROB_T 0.75f
#define IOU_T 0.5f
#define COV 10.0f

// ---- workspace layout (bytes) ----
#define SCORE_OFF 0u                 // float [B][NPIX]
#define FS_OFF    409600u            // float [B][NPIX]  frontal scores (raster order)
#define FIDX_OFF  819200u            // int   [B][NPIX]  frontal pixel idx
#define F_OFF     1228800u           // int   [B]
#define CIDX_OFF  1228864u           // int   [B][PRE_K]
#define CSC_OFF   1261632u           // float [B][PRE_K]
#define CBOX_OFF  1294400u           // float [B][PRE_K][4]
#define SUP_OFF   1425472u           // u64   [B][32][PRE_K]  (word-transposed)
#define KEEP_OFF  3522624u           // u64   [B][32]
#define NV_OFF    3523648u           // int   [B]
#define PAR_OFF   3523712u           // float [B][TOPK][5]  (muy,mux,dy,dx,p)

// out layout (floats)
#define OUT_HEAT_OFF 0
#define OUT_MASK_OFF 102400
#define OUT_BOX_OFF  512000
#define OUT_VAL_OFF  520000

typedef unsigned long long u64;

// -------- block exclusive scan over 256 ints (used by k_finalize) --------
__device__ __forceinline__ int block_scan_excl(int v, int tid, int* tmp, int* total) {
    tmp[tid] = v;
    __syncthreads();
    for (int off = 1; off < 256; off <<= 1) {
        int y = (tid >= off) ? tmp[tid - off] : 0;
        __syncthreads();
        tmp[tid] += y;
        __syncthreads();
    }
    int incl = tmp[tid];
    *total = tmp[255];
    __syncthreads();
    return incl - v;
}

// K1: per-pixel softmax-max / argmax / score
__global__ void k_score(const float* __restrict__ mask, float* __restrict__ score) {
    int b = blockIdx.y;
    int pix = blockIdx.x * 256 + threadIdx.x;
    const float* mp = mask + (size_t)b * NCH * NPIX + pix;
    float x0 = mp[0], x1 = mp[NPIX], x2 = mp[2 * NPIX], x3 = mp[3 * NPIX];
    float m = x0; int c = 0;
    if (x1 > m) { m = x1; c = 1; }
    if (x2 > m) { m = x2; c = 2; }
    if (x3 > m) { m = x3; c = 3; }
    float sum = ((expf(x0 - m) + expf(x1 - m)) + expf(x2 - m)) + expf(x3 - m);
    float prob = 1.0f / sum;
    bool frontal = (c != 0) && (prob > PROB_T);
    score[(size_t)b * NPIX + pix] = frontal ? prob : -1.0f;
}

// K2: ordered compaction, single pass. 1024 threads/image, 25 contiguous pixels
// per thread (raster order preserved), one wave-shuffle scan, 2 barriers.
// Non-frontal exclusive prefix is derived: nf_excl = pixel_start - f_excl.
#define PPT (NPIX / 1024)   // 25
__global__ void __launch_bounds__(1024)
k_compact(const float* __restrict__ score, float* __restrict__ fs,
          int* __restrict__ fidx, int* __restrict__ Fout,
          int* __restrict__ cand_idx, float* __restrict__ cand_score) {
    int b = blockIdx.x;
    int tid = threadIdx.x;           // 0..1023
    const float* sc = score + (size_t)b * NPIX;
    int p0 = tid * PPT;
    float v[PPT];
    int cnt = 0;
    #pragma unroll
    for (int j = 0; j < PPT; ++j) {
        v[j] = sc[p0 + j];
        cnt += (v[j] > 0.0f) ? 1 : 0;
    }
    // block exclusive scan of cnt over 1024 threads
    int lane = tid & 63, wv = tid >> 6;
    int incl = cnt;
    for (int off = 1; off < 64; off <<= 1) {
        int y = __shfl_up(incl, off);
        if (lane >= off) incl += y;
    }
    __shared__ int wtot[16];
    __shared__ int wpre[17];
    if (lane == 63) wtot[wv] = incl;
    __syncthreads();
    if (tid == 0) {
        int acc = 0;
        for (int k = 0; k < 16; ++k) { wpre[k] = acc; acc += wtot[k]; }
        wpre[16] = acc;
    }
    __syncthreads();
    int f_excl = wpre[wv] + (incl - cnt);
    int F = wpre[16];
    if (tid == 0) Fout[b] = F;
    // frontal pixels -> fs/fidx in raster order
    int w = f_excl;
    #pragma unroll
    for (int j = 0; j < PPT; ++j) {
        if (v[j] > 0.0f) {
            fs[(size_t)b * NPIX + w] = v[j];
            fidx[(size_t)b * NPIX + w] = p0 + j;
            ++w;
        }
    }
    // first (PRE_K - F) non-frontal pixels pad cand slots F.. (stable top_k padding)
    if (F < PRE_K) {
        int slot = F + (p0 - f_excl);
        if (slot < PRE_K) {
            #pragma unroll
            for (int j = 0; j < PPT; ++j) {
                if (!(v[j] > 0.0f)) {
                    if (slot < PRE_K) {
                        cand_idx[(size_t)b * PRE_K + slot] = p0 + j;
                        cand_score[(size_t)b * PRE_K + slot] = -1.0f;
                    }
                    ++slot;
                }
            }
        }
    }
}

// K3: exact rank of each frontal element (JAX top_k semantics: desc value, ties -> lower idx)
__global__ void k_rank(const float* __restrict__ fs, const int* __restrict__ fidx,
                       const int* __restrict__ Fout, int* __restrict__ cand_idx,
                       float* __restrict__ cand_score) {
    int b = blockIdx.y;
    int F = Fout[b];
    if (blockIdx.x * 256 >= F) return;
    int i = blockIdx.x * 256 + threadIdx.x;
    bool act = i < F;
    float si = 0.0f; int xi = 0;
    if (act) { si = fs[(size_t)b * NPIX + i]; xi = fidx[(size_t)b * NPIX + i]; }
    int rank = 0;
    __shared__ float ls[256];
    __shared__ int li[256];
    for (int base = 0; base < F; base += 256) {
        int j = base + threadIdx.x;
        if (j < F) { ls[threadIdx.x] = fs[(size_t)b * NPIX + j]; li[threadIdx.x] = fidx[(size_t)b * NPIX + j]; }
        __syncthreads();
        int lim = min(256, F - base);
        if (act) {
            for (int k = 0; k < lim; ++k) {
                float sj = ls[k]; int xj = li[k];
                rank += (sj > si || (sj == si && xj < xi)) ? 1 : 0;
            }
        }
        __syncthreads();
    }
    if (act && rank < PRE_K) {
        cand_idx[(size_t)b * PRE_K + rank] = xi;
        cand_score[(size_t)b * PRE_K + rank] = si;
    }
}

// K4: build candidate boxes (y,x,y,x) + bias
__global__ void k_boxes(const float* __restrict__ bias, const int* __restrict__ cand_idx,
                        float* __restrict__ cand_box) {
    int t = blockIdx.x * 256 + threadIdx.x;   // [0, BATCH*PRE_K)
    int b = t >> 11;
    int s = t & (PRE_K - 1);
    int pix = cand_idx[(size_t)b * PRE_K + s];
    float y = (float)(pix / W), x = (float)(pix % W);
    const float* bb = bias + (size_t)b * 4 * NPIX;
    float4 box;
    box.x = y + bb[0 * NPIX + pix];
    box.y = x + bb[1 * NPIX + pix];
    box.z = y + bb[2 * NPIX + pix];
    box.w = x + bb[3 * NPIX + pix];
    ((float4*)cand_box)[(size_t)b * PRE_K + s] = box;
}

// K5: suppression bitmatrix (bits only for j > i && iou > 0.5), stored transposed sup[b][w][i]
__global__ void k_iou(const float* __restrict__ cand_box, u64* __restrict__ sup) {
    int b = blockIdx.y;
    int r0 = blockIdx.x * 8;
    __shared__ float ly1[PRE_K], lx1[PRE_K], ly2[PRE_K], lx2[PRE_K], lar[PRE_K];
    for (int k = threadIdx.x; k < PRE_K; k += 256) {
        float4 v = ((const float4*)cand_box)[(size_t)b * PRE_K + k];
        ly1[k] = v.x; lx1[k] = v.y; ly2[k] = v.z; lx2[k] = v.w;
        lar[k] = (v.z - v.x) * (v.w - v.y);
    }
    __syncthreads();
    int lr = threadIdx.x >> 5;
    int w = threadIdx.x & 31;
    int i = r0 + lr;
    float ay1 = ly1[i], ax1 = lx1[i], ay2 = ly2[i], ax2 = lx2[i], aa = lar[i];
    u64 bits = 0;
    int jbase = w * 64;
    #pragma unroll 4
    for (int jj = 0; jj < 64; ++jj) {
        int jo = (jj + w) & 63;             // bank-conflict-free rotation
        int j = jbase + jo;
        if (j > i) {
            float lty = fmaxf(ay1, ly1[j]);
            float ltx = fmaxf(ax1, lx1[j]);
            float rby = fminf(ay2, ly2[j]);
            float rbx = fminf(ax2, lx2[j]);
            float wy = fmaxf(rby - lty, 0.0f);
            float wx = fmaxf(rbx - ltx, 0.0f);
            float inter = wy * wx;
            float iou = inter / ((aa + lar[j]) - inter);
            if (iou > IOU_T) bits |= (1ull << jo);
        }
    }
    sup[(size_t)b * 32 * PRE_K + (size_t)w * PRE_K + i] = bits;
}

// K6: serial greedy NMS, one wave per image. lane w owns keep word w (duplicated for lanes>=32).
__global__ void k_nms(const u64* __restrict__ sup, const int* __restrict__ Fout,
                      u64* __restrict__ keep) {
    int b = blockIdx.x;
    int lane = threadIdx.x;
    int w = lane & 31;
    int F = Fout[b];
    int V = F < PRE_K ? F : PRE_K;
    int lo = w * 64;
    int rem = V - lo;
    u64 kw = (rem >= 64) ? ~0ull : (rem <= 0 ? 0ull : ((1ull << rem) - 1ull));
    const u64* rowp = sup + (size_t)b * 32 * PRE_K + (size_t)w * PRE_K;
    u64 r[8], rn[8];
    if (V > 0) {
        #pragma unroll
        for (int k = 0; k < 8; ++k) r[k] = rowp[k];
        for (int i0 = 0; i0 < V; i0 += 8) {
            bool pf = (i0 + 8 < PRE_K);
            if (pf) {
                #pragma unroll
                for (int k = 0; k < 8; ++k) rn[k] = rowp[i0 + 8 + k];
            }
            #pragma unroll
            for (int k = 0; k < 8; ++k) {
                int ii = i0 + k;
                if (ii >= V) break;
                int ow = ii >> 6;
                u64 kb = __shfl(kw, ow);
                if ((kb >> (ii & 63)) & 1ull) kw &= ~r[k];
            }
            if (pf) {
                #pragma unroll
                for (int k = 0; k < 8; ++k) r[k] = rn[k];
            }
        }
    }
    if (lane < 32) keep[(size_t)b * 32 + w] = kw;
}

// K7: final top-500 (kept slots in order, then non-kept in slot order) + outputs + heat params
__global__ void k_finalize(const u64* __restrict__ keep, const float* __restrict__ cand_score,
                           const float* __restrict__ cand_box, float* __restrict__ out_boxes,
                           float* __restrict__ out_valid, float* __restrict__ params,
                           int* __restrict__ NV) {
    int b = blockIdx.x;
    int tid = threadIdx.x;
    __shared__ u64 kws[32];
    __shared__ int tmp[256];
    if (tid < 32) kws[tid] = keep[(size_t)b * 32 + tid];
    __syncthreads();
    int s0 = tid * 8;
    int bits8 = (int)((kws[s0 >> 6] >> (s0 & 63)) & 0xFFull);
    int cnt = __popc(bits8);
    int tot;
    int kpre = block_scan_excl(cnt, tid, tmp, &tot);
    int NK = tot;
    for (int k = 0; k < 8; ++k) {
        int s = s0 + k;
        int kept = (bits8 >> k) & 1;
        int pos = kept ? kpre : (NK + s - kpre);
        if (pos < TOPK) {
            float4 bx = ((const float4*)cand_box)[(size_t)b * PRE_K + s];
            ((float4*)out_boxes)[(size_t)b * TOPK + pos] = bx;
            out_valid[(size_t)b * TOPK + pos] = kept ? 1.0f : 0.0f;
            if (kept) {
                float scv = cand_score[(size_t)b * PRE_K + s];
                float* pp = params + ((size_t)b * TOPK + pos) * 5;
                pp[0] = (bx.x + bx.z) * 0.5f;   // muy
                pp[1] = (bx.y + bx.w) * 0.5f;   // mux
                pp[2] = (bx.z - bx.x) / COV;    // sigma_y / cov
                pp[3] = (bx.w - bx.y) / COV;    // sigma_x / cov
                pp[4] = scv;                    // prob
            }
        }
        kpre += kept;
    }
    if (tid == 0) NV[b] = NK < TOPK ? NK : TOPK;
}

// K8: heat map — max over valid boxes of exp(-0.5 |z|^2) * p  (invalid boxes contribute exactly 0)
__global__ void k_heat(const float* __restrict__ params, const int* __restrict__ NV,
                       float* __restrict__ heat) {
    int b = blockIdx.y;
    int pix = blockIdx.x * 256 + threadIdx.x;
    int nv = NV[b];
    __shared__ float lp[TOPK * 5];
    for (int k = threadIdx.x; k < nv * 5; k += 256) lp[k] = params[(size_t)b * TOPK * 5 + k];
    __syncthreads();
    float py = (float)(pix / W), px = (float)(pix % W);
    float m = 0.0f;
    for (int t = 0; t < nv; ++t) {
        float muy = lp[t * 5 + 0], mux = lp[t * 5 + 1];
        float dy = lp[t * 5 + 2], dx = lp[t * 5 + 3], p = lp[t * 5 + 4];
        float zy = (py - muy) / dy;
        float zx = (px - mux) / dx;
        float g = expf(-0.5f * (zy * zy + zx * zx)) * p;
        m = fmaxf(m, g);
    }
    heat[(size_t)b * NPIX + pix] = m;
}

extern "C" void kernel_launch(void* const* d_in, const int* in_sizes, int n_in,
                              void* d_out, int out_size, void* d_ws, size_t ws_size,
                              hipStream_t stream) {
    const float* mask = (const float*)d_in[0];
    const float* bias = (const float*)d_in[1];
    float* out = (float*)d_out;
    char* ws = (char*)d_ws;

    float* score      = (float*)(ws + SCORE_OFF);
    float* fs         = (float*)(ws + FS_OFF);
    int*   fidx       = (int*)(ws + FIDX_OFF);
    int*   Fout       = (int*)(ws + F_OFF);
    int*   cand_idx   = (int*)(ws + CIDX_OFF);
    float* cand_score = (float*)(ws + CSC_OFF);
    float* cand_box   = (float*)(ws + CBOX_OFF);
    u64*   sup        = (u64*)(ws + SUP_OFF);
    u64*   keep       = (u64*)(ws + KEEP_OFF);
    int*   NV         = (int*)(ws + NV_OFF);
    float* params     = (float*)(ws + PAR_OFF);

    // mask passthrough (output 1)
    hipMemcpyAsync(out + OUT_MASK_OFF, mask, (size_t)BATCH * NCH * NPIX * sizeof(float),
                   hipMemcpyDeviceToDevice, stream);

    dim3 g100(NPIX / 256, BATCH);
    k_score<<<g100, 256, 0, stream>>>(mask, score);
    k_compact<<<BATCH, 1024, 0, stream>>>(score, fs, fidx, Fout, cand_idx, cand_score);
    k_rank<<<g100, 256, 0, stream>>>(fs, fidx, Fout, cand_idx, cand_score);
    k_boxes<<<dim3(BATCH * PRE_K / 256), 256, 0, stream>>>(bias, cand_idx, cand_box);
    k_iou<<<dim3(PRE_K / 8, BATCH), 256, 0, stream>>>(cand_box, sup);
    k_nms<<<BATCH, 64, 0, stream>>>(sup, Fout, keep);
    k_finalize<<<BATCH, 256, 0, stream>>>(keep, cand_score, cand_box,
                                          out + OUT_BOX_OFF, out + OUT_VAL_OFF, params, NV);
    k_heat<<<g100, 256, 0, stream>>>(params, NV, out + OUT_HEAT_OFF);
}

// Round 3
// 241.284 us; speedup vs baseline: 1.8663x; 1.3953x over previous
//
#include <hip/hip_runtime.h>
#include <math.h>

#define BATCH 4
#define NCH 4
#define H 160
#define W 160
#define NPIX (H * W)          // 25600
#define PRE_K 2048
#define TOPK 500
#define PROB_T 0.75f
#define IOU_T 0.5f
#define COV 10.0f

// ---- workspace layout (bytes) ----
#define SCORE_OFF 0u                 // float [B][NPIX]
#define FS_OFF    409600u            // float [B][NPIX]  frontal scores (raster order)
#define FIDX_OFF  819200u            // int   [B][NPIX]  frontal pixel idx
#define F_OFF     1228800u           // int   [B]
#define CIDX_OFF  1228864u           // int   [B][PRE_K]
#define CSC_OFF   1261632u           // float [B][PRE_K]
#define CBOX_OFF  1294400u           // float [B][PRE_K][4]
#define SUP_OFF   1425472u           // u64   [B][32][PRE_K]  (word-transposed)
#define KEEP_OFF  3522624u           // u64   [B][32]
#define NV_OFF    3523648u           // int   [B]
#define PAR_OFF   3523712u           // float [B][TOPK][5]  (muy,mux,dy,dx,p)

// out layout (floats)
#define OUT_HEAT_OFF 0
#define OUT_MASK_OFF 102400
#define OUT_BOX_OFF  512000
#define OUT_VAL_OFF  520000

typedef unsigned long long u64;

// -------- block exclusive scan over 256 ints (used by k_finalize) --------
__device__ __forceinline__ int block_scan_excl(int v, int tid, int* tmp, int* total) {
    tmp[tid] = v;
    __syncthreads();
    for (int off = 1; off < 256; off <<= 1) {
        int y = (tid >= off) ? tmp[tid - off] : 0;
        __syncthreads();
        tmp[tid] += y;
        __syncthreads();
    }
    int incl = tmp[tid];
    *total = tmp[255];
    __syncthreads();
    return incl - v;
}

// K1: per-pixel softmax-max / argmax / score
__global__ void k_score(const float* __restrict__ mask, float* __restrict__ score) {
    int b = blockIdx.y;
    int pix = blockIdx.x * 256 + threadIdx.x;
    const float* mp = mask + (size_t)b * NCH * NPIX + pix;
    float x0 = mp[0], x1 = mp[NPIX], x2 = mp[2 * NPIX], x3 = mp[3 * NPIX];
    float m = x0; int c = 0;
    if (x1 > m) { m = x1; c = 1; }
    if (x2 > m) { m = x2; c = 2; }
    if (x3 > m) { m = x3; c = 3; }
    float sum = ((expf(x0 - m) + expf(x1 - m)) + expf(x2 - m)) + expf(x3 - m);
    float prob = 1.0f / sum;
    bool frontal = (c != 0) && (prob > PROB_T);
    score[(size_t)b * NPIX + pix] = frontal ? prob : -1.0f;
}

// K2: ordered compaction, single pass. 1024 threads/image, 25 contiguous pixels
// per thread (raster order preserved), one wave-shuffle scan, 2 barriers.
#define PPT (NPIX / 1024)   // 25
__global__ void __launch_bounds__(1024)
k_compact(const float* __restrict__ score, float* __restrict__ fs,
          int* __restrict__ fidx, int* __restrict__ Fout,
          int* __restrict__ cand_idx, float* __restrict__ cand_score) {
    int b = blockIdx.x;
    int tid = threadIdx.x;           // 0..1023
    const float* sc = score + (size_t)b * NPIX;
    int p0 = tid * PPT;
    float v[PPT];
    int cnt = 0;
    #pragma unroll
    for (int j = 0; j < PPT; ++j) {
        v[j] = sc[p0 + j];
        cnt += (v[j] > 0.0f) ? 1 : 0;
    }
    int lane = tid & 63, wv = tid >> 6;
    int incl = cnt;
    for (int off = 1; off < 64; off <<= 1) {
        int y = __shfl_up(incl, off);
        if (lane >= off) incl += y;
    }
    __shared__ int wtot[16];
    __shared__ int wpre[17];
    if (lane == 63) wtot[wv] = incl;
    __syncthreads();
    if (tid == 0) {
        int acc = 0;
        for (int k = 0; k < 16; ++k) { wpre[k] = acc; acc += wtot[k]; }
        wpre[16] = acc;
    }
    __syncthreads();
    int f_excl = wpre[wv] + (incl - cnt);
    int F = wpre[16];
    if (tid == 0) Fout[b] = F;
    int w = f_excl;
    #pragma unroll
    for (int j = 0; j < PPT; ++j) {
        if (v[j] > 0.0f) {
            fs[(size_t)b * NPIX + w] = v[j];
            fidx[(size_t)b * NPIX + w] = p0 + j;
            ++w;
        }
    }
    if (F < PRE_K) {
        int slot = F + (p0 - f_excl);
        if (slot < PRE_K) {
            #pragma unroll
            for (int j = 0; j < PPT; ++j) {
                if (!(v[j] > 0.0f)) {
                    if (slot < PRE_K) {
                        cand_idx[(size_t)b * PRE_K + slot] = p0 + j;
                        cand_score[(size_t)b * PRE_K + slot] = -1.0f;
                    }
                    ++slot;
                }
            }
        }
    }
}

// K3: exact rank of each frontal element (JAX top_k semantics: desc value, ties -> lower idx)
__global__ void k_rank(const float* __restrict__ fs, const int* __restrict__ fidx,
                       const int* __restrict__ Fout, int* __restrict__ cand_idx,
                       float* __restrict__ cand_score) {
    int b = blockIdx.y;
    int F = Fout[b];
    if (blockIdx.x * 256 >= F) return;
    int i = blockIdx.x * 256 + threadIdx.x;
    bool act = i < F;
    float si = 0.0f; int xi = 0;
    if (act) { si = fs[(size_t)b * NPIX + i]; xi = fidx[(size_t)b * NPIX + i]; }
    int rank = 0;
    __shared__ float ls[256];
    __shared__ int li[256];
    for (int base = 0; base < F; base += 256) {
        int j = base + threadIdx.x;
        if (j < F) { ls[threadIdx.x] = fs[(size_t)b * NPIX + j]; li[threadIdx.x] = fidx[(size_t)b * NPIX + j]; }
        __syncthreads();
        int lim = min(256, F - base);
        if (act) {
            for (int k = 0; k < lim; ++k) {
                float sj = ls[k]; int xj = li[k];
                rank += (sj > si || (sj == si && xj < xi)) ? 1 : 0;
            }
        }
        __syncthreads();
    }
    if (act && rank < PRE_K) {
        cand_idx[(size_t)b * PRE_K + rank] = xi;
        cand_score[(size_t)b * PRE_K + rank] = si;
    }
}

// K4: build candidate boxes (y,x,y,x) + bias
__global__ void k_boxes(const float* __restrict__ bias, const int* __restrict__ cand_idx,
                        float* __restrict__ cand_box) {
    int t = blockIdx.x * 256 + threadIdx.x;   // [0, BATCH*PRE_K)
    int b = t >> 11;
    int s = t & (PRE_K - 1);
    int pix = cand_idx[(size_t)b * PRE_K + s];
    float y = (float)(pix / W), x = (float)(pix % W);
    const float* bb = bias + (size_t)b * 4 * NPIX;
    float4 box;
    box.x = y + bb[0 * NPIX + pix];
    box.y = x + bb[1 * NPIX + pix];
    box.z = y + bb[2 * NPIX + pix];
    box.w = x + bb[3 * NPIX + pix];
    ((float4*)cand_box)[(size_t)b * PRE_K + s] = box;
}

// K5: suppression bitmatrix (bits only for j > i && iou > 0.5), stored transposed sup[b][w][i]
__global__ void k_iou(const float* __restrict__ cand_box, u64* __restrict__ sup) {
    int b = blockIdx.y;
    int r0 = blockIdx.x * 8;
    __shared__ float ly1[PRE_K], lx1[PRE_K], ly2[PRE_K], lx2[PRE_K], lar[PRE_K];
    for (int k = threadIdx.x; k < PRE_K; k += 256) {
        float4 v = ((const float4*)cand_box)[(size_t)b * PRE_K + k];
        ly1[k] = v.x; lx1[k] = v.y; ly2[k] = v.z; lx2[k] = v.w;
        lar[k] = (v.z - v.x) * (v.w - v.y);
    }
    __syncthreads();
    int lr = threadIdx.x >> 5;
    int w = threadIdx.x & 31;
    int i = r0 + lr;
    float ay1 = ly1[i], ax1 = lx1[i], ay2 = ly2[i], ax2 = lx2[i], aa = lar[i];
    u64 bits = 0;
    int jbase = w * 64;
    #pragma unroll 4
    for (int jj = 0; jj < 64; ++jj) {
        int jo = (jj + w) & 63;             // bank-conflict-free rotation
        int j = jbase + jo;
        if (j > i) {
            float lty = fmaxf(ay1, ly1[j]);
            float ltx = fmaxf(ax1, lx1[j]);
            float rby = fminf(ay2, ly2[j]);
            float rbx = fminf(ax2, lx2[j]);
            float wy = fmaxf(rby - lty, 0.0f);
            float wx = fmaxf(rbx - ltx, 0.0f);
            float inter = wy * wx;
            float iou = inter / ((aa + lar[j]) - inter);
            if (iou > IOU_T) bits |= (1ull << jo);
        }
    }
    sup[(size_t)b * 32 * PRE_K + (size_t)w * PRE_K + i] = bits;
}

// K6: serial greedy NMS, one wave per image. lane w owns keep word w (duplicated for lanes>=32).
__global__ void k_nms(const u64* __restrict__ sup, const int* __restrict__ Fout,
                      u64* __restrict__ keep) {
    int b = blockIdx.x;
    int lane = threadIdx.x;
    int w = lane & 31;
    int F = Fout[b];
    int V = F < PRE_K ? F : PRE_K;
    int lo = w * 64;
    int rem = V - lo;
    u64 kw = (rem >= 64) ? ~0ull : (rem <= 0 ? 0ull : ((1ull << rem) - 1ull));
    const u64* rowp = sup + (size_t)b * 32 * PRE_K + (size_t)w * PRE_K;
    u64 r[8], rn[8];
    if (V > 0) {
        #pragma unroll
        for (int k = 0; k < 8; ++k) r[k] = rowp[k];
        for (int i0 = 0; i0 < V; i0 += 8) {
            bool pf = (i0 + 8 < PRE_K);
            if (pf) {
                #pragma unroll
                for (int k = 0; k < 8; ++k) rn[k] = rowp[i0 + 8 + k];
            }
            #pragma unroll
            for (int k = 0; k < 8; ++k) {
                int ii = i0 + k;
                if (ii >= V) break;
                int ow = ii >> 6;
                u64 kb = __shfl(kw, ow);
                if ((kb >> (ii & 63)) & 1ull) kw &= ~r[k];
            }
            if (pf) {
                #pragma unroll
                for (int k = 0; k < 8; ++k) r[k] = rn[k];
            }
        }
    }
    if (lane < 32) keep[(size_t)b * 32 + w] = kw;
}

// K7: final top-500 (kept slots in order, then non-kept in slot order) + outputs + heat params
__global__ void k_finalize(const u64* __restrict__ keep, const float* __restrict__ cand_score,
                           const float* __restrict__ cand_box, float* __restrict__ out_boxes,
                           float* __restrict__ out_valid, float* __restrict__ params,
                           int* __restrict__ NV) {
    int b = blockIdx.x;
    int tid = threadIdx.x;
    __shared__ u64 kws[32];
    __shared__ int tmp[256];
    if (tid < 32) kws[tid] = keep[(size_t)b * 32 + tid];
    __syncthreads();
    int s0 = tid * 8;
    int bits8 = (int)((kws[s0 >> 6] >> (s0 & 63)) & 0xFFull);
    int cnt = __popc(bits8);
    int tot;
    int kpre = block_scan_excl(cnt, tid, tmp, &tot);
    int NK = tot;
    for (int k = 0; k < 8; ++k) {
        int s = s0 + k;
        int kept = (bits8 >> k) & 1;
        int pos = kept ? kpre : (NK + s - kpre);
        if (pos < TOPK) {
            float4 bx = ((const float4*)cand_box)[(size_t)b * PRE_K + s];
            ((float4*)out_boxes)[(size_t)b * TOPK + pos] = bx;
            out_valid[(size_t)b * TOPK + pos] = kept ? 1.0f : 0.0f;
            if (kept) {
                float scv = cand_score[(size_t)b * PRE_K + s];
                float* pp = params + ((size_t)b * TOPK + pos) * 5;
                pp[0] = (bx.x + bx.z) * 0.5f;   // muy
                pp[1] = (bx.y + bx.w) * 0.5f;   // mux
                pp[2] = (bx.z - bx.x) / COV;    // sigma_y / cov
                pp[3] = (bx.w - bx.y) / COV;    // sigma_x / cov
                pp[4] = scv;                    // prob
            }
        }
        kpre += kept;
    }
    if (tid == 0) NV[b] = NK < TOPK ? NK : TOPK;
}

// K8: tiled heat map. One 256-thread block per 16x16 tile; cull boxes by
// min z^2 over the tile (z^2 > 40 => g < 2.5e-9, below output noise floor),
// then each pixel evaluates only surviving boxes. Max is commutative, so
// LDS-append order is irrelevant.
#define TILE 16
#define TPL (W / TILE)   // 10 tiles per row
__global__ void k_heat(const float* __restrict__ params, const int* __restrict__ NV,
                       float* __restrict__ heat) {
    int b = blockIdx.y;
    int ty0 = (blockIdx.x / TPL) * TILE;
    int tx0 = (blockIdx.x % TPL) * TILE;
    int tid = threadIdx.x;
    int nv = NV[b];
    __shared__ float lp[TOPK * 5];
    __shared__ int cntS;
    if (tid == 0) cntS = 0;
    __syncthreads();
    for (int t = tid; t < nv; t += 256) {
        const float* pp = params + ((size_t)b * TOPK + t) * 5;
        float muy = pp[0], mux = pp[1], dy = pp[2], dx = pp[3], p = pp[4];
        // min |pixel - mu| over tile rect, per axis
        float cy = fmaxf(fmaxf((float)ty0 - muy, muy - (float)(ty0 + TILE - 1)), 0.0f);
        float cx = fmaxf(fmaxf((float)tx0 - mux, mux - (float)(tx0 + TILE - 1)), 0.0f);
        float zy = cy / fabsf(dy);
        float zx = cx / fabsf(dx);
        float z2 = zy * zy + zx * zx;
        if (!(z2 > 40.0f)) {                 // keep NaN (dy==0 && on-line) cases
            int idx = atomicAdd(&cntS, 1);
            float* q = lp + idx * 5;
            q[0] = muy; q[1] = mux; q[2] = dy; q[3] = dx; q[4] = p;
        }
    }
    __syncthreads();
    int n = cntS;
    float py = (float)(ty0 + (tid >> 4));
    float px = (float)(tx0 + (tid & 15));
    float m = 0.0f;
    for (int t = 0; t < n; ++t) {
        float muy = lp[t * 5 + 0], mux = lp[t * 5 + 1];
        float dy = lp[t * 5 + 2], dx = lp[t * 5 + 3], p = lp[t * 5 + 4];
        float zy = (py - muy) / dy;
        float zx = (px - mux) / dx;
        float g = expf(-0.5f * (zy * zy + zx * zx)) * p;
        m = fmaxf(m, g);
    }
    heat[(size_t)b * NPIX + (ty0 + (tid >> 4)) * W + tx0 + (tid & 15)] = m;
}

extern "C" void kernel_launch(void* const* d_in, const int* in_sizes, int n_in,
                              void* d_out, int out_size, void* d_ws, size_t ws_size,
                              hipStream_t stream) {
    const float* mask = (const float*)d_in[0];
    const float* bias = (const float*)d_in[1];
    float* out = (float*)d_out;
    char* ws = (char*)d_ws;

    float* score      = (float*)(ws + SCORE_OFF);
    float* fs         = (float*)(ws + FS_OFF);
    int*   fidx       = (int*)(ws + FIDX_OFF);
    int*   Fout       = (int*)(ws + F_OFF);
    int*   cand_idx   = (int*)(ws + CIDX_OFF);
    float* cand_score = (float*)(ws + CSC_OFF);
    float* cand_box   = (float*)(ws + CBOX_OFF);
    u64*   sup        = (u64*)(ws + SUP_OFF);
    u64*   keep       = (u64*)(ws + KEEP_OFF);
    int*   NV         = (int*)(ws + NV_OFF);
    float* params     = (float*)(ws + PAR_OFF);

    // mask passthrough (output 1)
    hipMemcpyAsync(out + OUT_MASK_OFF, mask, (size_t)BATCH * NCH * NPIX * sizeof(float),
                   hipMemcpyDeviceToDevice, stream);

    dim3 g100(NPIX / 256, BATCH);
    k_score<<<g100, 256, 0, stream>>>(mask, score);
    k_compact<<<BATCH, 1024, 0, stream>>>(score, fs, fidx, Fout, cand_idx, cand_score);
    k_rank<<<g100, 256, 0, stream>>>(fs, fidx, Fout, cand_idx, cand_score);
    k_boxes<<<dim3(BATCH * PRE_K / 256), 256, 0, stream>>>(bias, cand_idx, cand_box);
    k_iou<<<dim3(PRE_K / 8, BATCH), 256, 0, stream>>>(cand_box, sup);
    k_nms<<<BATCH, 64, 0, stream>>>(sup, Fout, keep);
    k_finalize<<<BATCH, 256, 0, stream>>>(keep, cand_score, cand_box,
                                          out + OUT_BOX_OFF, out + OUT_VAL_OFF, params, NV);
    k_heat<<<dim3(TPL * (H / TILE), BATCH), 256, 0, stream>>>(params, NV, out + OUT_HEAT_OFF);
}

// Round 4
// 193.096 us; speedup vs baseline: 2.3320x; 1.2496x over previous
//
#include <hip/hip_runtime.h>
#include <math.h>

#define BATCH 4
#define NCH 4
#define H 160
#define W 160
#define NPIX (H * W)          // 25600
#define PRE_K 2048
#define TOPK 500
#define PROB_T 0.75f
#define IOU_T 0.5f
#define COV 10.0f

// ---- workspace layout (bytes) ----
#define SCORE_OFF 0u                 // float [B][NPIX]
#define FS_OFF    409600u            // float [B][NPIX]  frontal scores (raster order)
#define FIDX_OFF  819200u            // int   [B][NPIX]  frontal pixel idx
#define F_OFF     1228800u           // int   [B]
#define CIDX_OFF  1228864u           // int   [B][PRE_K]
#define CSC_OFF   1261632u           // float [B][PRE_K]
#define CBOX_OFF  1294400u           // float [B][PRE_K][4]
#define SUP_OFF   1425472u           // u32   [B][PRE_K][64]  (row-major, coalesced rows)
#define KEEP_OFF  3522624u           // u32   [B][64]
#define NV_OFF    3523648u           // int   [B]
#define PAR_OFF   3523712u           // float [B][TOPK][5]  (muy,mux,dy,dx,p)

// out layout (floats)
#define OUT_HEAT_OFF 0
#define OUT_MASK_OFF 102400
#define OUT_BOX_OFF  512000
#define OUT_VAL_OFF  520000

typedef unsigned long long u64;
typedef unsigned int u32;

// -------- block exclusive scan over 256 ints (used by k_finalize) --------
__device__ __forceinline__ int block_scan_excl(int v, int tid, int* tmp, int* total) {
    tmp[tid] = v;
    __syncthreads();
    for (int off = 1; off < 256; off <<= 1) {
        int y = (tid >= off) ? tmp[tid - off] : 0;
        __syncthreads();
        tmp[tid] += y;
        __syncthreads();
    }
    int incl = tmp[tid];
    *total = tmp[255];
    __syncthreads();
    return incl - v;
}

// K1: per-pixel softmax-max / argmax / score
__global__ void k_score(const float* __restrict__ mask, float* __restrict__ score) {
    int b = blockIdx.y;
    int pix = blockIdx.x * 256 + threadIdx.x;
    const float* mp = mask + (size_t)b * NCH * NPIX + pix;
    float x0 = mp[0], x1 = mp[NPIX], x2 = mp[2 * NPIX], x3 = mp[3 * NPIX];
    float m = x0; int c = 0;
    if (x1 > m) { m = x1; c = 1; }
    if (x2 > m) { m = x2; c = 2; }
    if (x3 > m) { m = x3; c = 3; }
    float sum = ((expf(x0 - m) + expf(x1 - m)) + expf(x2 - m)) + expf(x3 - m);
    float prob = 1.0f / sum;
    bool frontal = (c != 0) && (prob > PROB_T);
    score[(size_t)b * NPIX + pix] = frontal ? prob : -1.0f;
}

// K2: ordered compaction, single pass. 1024 threads/image, 25 contiguous pixels
// per thread (raster order preserved), one wave-shuffle scan, 2 barriers.
#define PPT (NPIX / 1024)   // 25
__global__ void __launch_bounds__(1024)
k_compact(const float* __restrict__ score, float* __restrict__ fs,
          int* __restrict__ fidx, int* __restrict__ Fout,
          int* __restrict__ cand_idx, float* __restrict__ cand_score) {
    int b = blockIdx.x;
    int tid = threadIdx.x;           // 0..1023
    const float* sc = score + (size_t)b * NPIX;
    int p0 = tid * PPT;
    float v[PPT];
    int cnt = 0;
    #pragma unroll
    for (int j = 0; j < PPT; ++j) {
        v[j] = sc[p0 + j];
        cnt += (v[j] > 0.0f) ? 1 : 0;
    }
    int lane = tid & 63, wv = tid >> 6;
    int incl = cnt;
    for (int off = 1; off < 64; off <<= 1) {
        int y = __shfl_up(incl, off);
        if (lane >= off) incl += y;
    }
    __shared__ int wtot[16];
    __shared__ int wpre[17];
    if (lane == 63) wtot[wv] = incl;
    __syncthreads();
    if (tid == 0) {
        int acc = 0;
        for (int k = 0; k < 16; ++k) { wpre[k] = acc; acc += wtot[k]; }
        wpre[16] = acc;
    }
    __syncthreads();
    int f_excl = wpre[wv] + (incl - cnt);
    int F = wpre[16];
    if (tid == 0) Fout[b] = F;
    int w = f_excl;
    #pragma unroll
    for (int j = 0; j < PPT; ++j) {
        if (v[j] > 0.0f) {
            fs[(size_t)b * NPIX + w] = v[j];
            fidx[(size_t)b * NPIX + w] = p0 + j;
            ++w;
        }
    }
    if (F < PRE_K) {
        int slot = F + (p0 - f_excl);
        if (slot < PRE_K) {
            #pragma unroll
            for (int j = 0; j < PPT; ++j) {
                if (!(v[j] > 0.0f)) {
                    if (slot < PRE_K) {
                        cand_idx[(size_t)b * PRE_K + slot] = p0 + j;
                        cand_score[(size_t)b * PRE_K + slot] = -1.0f;
                    }
                    ++slot;
                }
            }
        }
    }
}

// K3: exact rank of each frontal element (JAX top_k semantics: desc value, ties -> lower idx)
__global__ void k_rank(const float* __restrict__ fs, const int* __restrict__ fidx,
                       const int* __restrict__ Fout, int* __restrict__ cand_idx,
                       float* __restrict__ cand_score) {
    int b = blockIdx.y;
    int F = Fout[b];
    if (blockIdx.x * 256 >= F) return;
    int i = blockIdx.x * 256 + threadIdx.x;
    bool act = i < F;
    float si = 0.0f; int xi = 0;
    if (act) { si = fs[(size_t)b * NPIX + i]; xi = fidx[(size_t)b * NPIX + i]; }
    int rank = 0;
    __shared__ float ls[256];
    __shared__ int li[256];
    for (int base = 0; base < F; base += 256) {
        int j = base + threadIdx.x;
        if (j < F) { ls[threadIdx.x] = fs[(size_t)b * NPIX + j]; li[threadIdx.x] = fidx[(size_t)b * NPIX + j]; }
        __syncthreads();
        int lim = min(256, F - base);
        if (act) {
            for (int k = 0; k < lim; ++k) {
                float sj = ls[k]; int xj = li[k];
                rank += (sj > si || (sj == si && xj < xi)) ? 1 : 0;
            }
        }
        __syncthreads();
    }
    if (act && rank < PRE_K) {
        cand_idx[(size_t)b * PRE_K + rank] = xi;
        cand_score[(size_t)b * PRE_K + rank] = si;
    }
}

// K4: build candidate boxes (y,x,y,x) + bias
__global__ void k_boxes(const float* __restrict__ bias, const int* __restrict__ cand_idx,
                        float* __restrict__ cand_box) {
    int t = blockIdx.x * 256 + threadIdx.x;   // [0, BATCH*PRE_K)
    int b = t >> 11;
    int s = t & (PRE_K - 1);
    int pix = cand_idx[(size_t)b * PRE_K + s];
    float y = (float)(pix / W), x = (float)(pix % W);
    const float* bb = bias + (size_t)b * 4 * NPIX;
    float4 box;
    box.x = y + bb[0 * NPIX + pix];
    box.y = x + bb[1 * NPIX + pix];
    box.z = y + bb[2 * NPIX + pix];
    box.w = x + bb[3 * NPIX + pix];
    ((float4*)cand_box)[(size_t)b * PRE_K + s] = box;
}

// K5: suppression bitmatrix, u32 granularity. sup[b][i][w] = bits for boxes
// j in [w*32, w*32+32) vs row i (only j > i && iou > 0.5). Row-contiguous:
// one row = 256B, coalesced write here and coalesced read in k_nms.
// 512 threads = 8 rows x 64 word-lanes.
__global__ void __launch_bounds__(512)
k_iou(const float* __restrict__ cand_box, u32* __restrict__ sup) {
    int b = blockIdx.y;
    int r0 = blockIdx.x * 8;
    __shared__ float ly1[PRE_K], lx1[PRE_K], ly2[PRE_K], lx2[PRE_K], lar[PRE_K];
    for (int k = threadIdx.x; k < PRE_K; k += 512) {
        float4 v = ((const float4*)cand_box)[(size_t)b * PRE_K + k];
        ly1[k] = v.x; lx1[k] = v.y; ly2[k] = v.z; lx2[k] = v.w;
        lar[k] = (v.z - v.x) * (v.w - v.y);
    }
    __syncthreads();
    int lr = threadIdx.x >> 6;      // 0..7
    int w = threadIdx.x & 63;       // 0..63
    int i = r0 + lr;
    float ay1 = ly1[i], ax1 = lx1[i], ay2 = ly2[i], ax2 = lx2[i], aa = lar[i];
    u32 bits = 0;
    int jbase = w * 32;
    #pragma unroll 4
    for (int jj = 0; jj < 32; ++jj) {
        int jo = (jj + w) & 31;             // bank-conflict-free rotation
        int j = jbase + jo;
        if (j > i) {
            float lty = fmaxf(ay1, ly1[j]);
            float ltx = fmaxf(ax1, lx1[j]);
            float rby = fminf(ay2, ly2[j]);
            float rbx = fminf(ax2, lx2[j]);
            float wy = fmaxf(rby - lty, 0.0f);
            float wx = fmaxf(rbx - ltx, 0.0f);
            float inter = wy * wx;
            float iou = inter / ((aa + lar[j]) - inter);
            if (iou > IOU_T) bits |= (1u << jo);
        }
    }
    sup[((size_t)b * PRE_K + i) * 64 + w] = bits;
}

// K6: serial greedy NMS, one wave per image. Lane w owns keep word w
// (boxes [w*32, w*32+32)). Chain ops: readlane (VALU, uniform lane idx)
// instead of shfl; zero rows/groups skipped via __any; rows prefetched
// 2 groups (32 rows = 8KB) ahead, coalesced 256B per row.
__global__ void __launch_bounds__(64)
k_nms(const u32* __restrict__ sup, const int* __restrict__ Fout,
      u32* __restrict__ keep) {
    int b = blockIdx.x;
    int w = threadIdx.x;            // 0..63
    int F = Fout[b];
    int V = F < PRE_K ? F : PRE_K;
    int rem = V - w * 32;
    u32 kw = (rem >= 32) ? 0xFFFFFFFFu : (rem <= 0 ? 0u : ((1u << rem) - 1u));
    const u32* rowp = sup + (size_t)b * PRE_K * 64 + w;
    u32 r[16], rn[16], rnn[16];
    #pragma unroll
    for (int k = 0; k < 16; ++k) {
        r[k]  = rowp[(size_t)k * 64];
        rn[k] = rowp[(size_t)(16 + k) * 64];
    }
    for (int i0 = 0; i0 < V; i0 += 16) {
        #pragma unroll
        for (int k = 0; k < 16; ++k) {
            int idx = i0 + 32 + k;
            rnn[k] = rowp[(size_t)(idx < PRE_K ? idx : PRE_K - 1) * 64];
        }
        u32 o = 0;
        #pragma unroll
        for (int k = 0; k < 16; ++k) o |= r[k];
        if (__any(o != 0)) {
            #pragma unroll
            for (int k = 0; k < 16; ++k) {
                int ii = i0 + k;
                if (ii >= V) break;
                if (__any(r[k] != 0)) {
                    u32 kb = (u32)__builtin_amdgcn_readlane((int)kw, ii >> 5);
                    if ((kb >> (ii & 31)) & 1u) kw &= ~r[k];
                }
            }
        }
        #pragma unroll
        for (int k = 0; k < 16; ++k) { r[k] = rn[k]; rn[k] = rnn[k]; }
    }
    keep[(size_t)b * 64 + w] = kw;
}

// K7: final top-500 (kept slots in order, then non-kept in slot order) + outputs + heat params
__global__ void k_finalize(const u32* __restrict__ keep, const float* __restrict__ cand_score,
                           const float* __restrict__ cand_box, float* __restrict__ out_boxes,
                           float* __restrict__ out_valid, float* __restrict__ params,
                           int* __restrict__ NV) {
    int b = blockIdx.x;
    int tid = threadIdx.x;
    __shared__ u32 kws[64];
    __shared__ int tmp[256];
    if (tid < 64) kws[tid] = keep[(size_t)b * 64 + tid];
    __syncthreads();
    int s0 = tid * 8;
    int bits8 = (int)((kws[s0 >> 5] >> (s0 & 31)) & 0xFFu);
    int cnt = __popc(bits8);
    int tot;
    int kpre = block_scan_excl(cnt, tid, tmp, &tot);
    int NK = tot;
    for (int k = 0; k < 8; ++k) {
        int s = s0 + k;
        int kept = (bits8 >> k) & 1;
        int pos = kept ? kpre : (NK + s - kpre);
        if (pos < TOPK) {
            float4 bx = ((const float4*)cand_box)[(size_t)b * PRE_K + s];
            ((float4*)out_boxes)[(size_t)b * TOPK + pos] = bx;
            out_valid[(size_t)b * TOPK + pos] = kept ? 1.0f : 0.0f;
            if (kept) {
                float scv = cand_score[(size_t)b * PRE_K + s];
                float* pp = params + ((size_t)b * TOPK + pos) * 5;
                pp[0] = (bx.x + bx.z) * 0.5f;   // muy
                pp[1] = (bx.y + bx.w) * 0.5f;   // mux
                pp[2] = (bx.z - bx.x) / COV;    // sigma_y / cov
                pp[3] = (bx.w - bx.y) / COV;    // sigma_x / cov
                pp[4] = scv;                    // prob
            }
        }
        kpre += kept;
    }
    if (tid == 0) NV[b] = NK < TOPK ? NK : TOPK;
}

// K8: tiled heat map. One 256-thread block per 16x16 tile; cull boxes by
// min z^2 over the tile (z^2 > 40 => g < 2.5e-9, below output noise floor),
// then each pixel evaluates only surviving boxes.
#define TILE 16
#define TPL (W / TILE)   // 10 tiles per row
__global__ void k_heat(const float* __restrict__ params, const int* __restrict__ NV,
                       float* __restrict__ heat) {
    int b = blockIdx.y;
    int ty0 = (blockIdx.x / TPL) * TILE;
    int tx0 = (blockIdx.x % TPL) * TILE;
    int tid = threadIdx.x;
    int nv = NV[b];
    __shared__ float lp[TOPK * 5];
    __shared__ int cntS;
    if (tid == 0) cntS = 0;
    __syncthreads();
    for (int t = tid; t < nv; t += 256) {
        const float* pp = params + ((size_t)b * TOPK + t) * 5;
        float muy = pp[0], mux = pp[1], dy = pp[2], dx = pp[3], p = pp[4];
        float cy = fmaxf(fmaxf((float)ty0 - muy, muy - (float)(ty0 + TILE - 1)), 0.0f);
        float cx = fmaxf(fmaxf((float)tx0 - mux, mux - (float)(tx0 + TILE - 1)), 0.0f);
        float zy = cy / fabsf(dy);
        float zx = cx / fabsf(dx);
        float z2 = zy * zy + zx * zx;
        if (!(z2 > 40.0f)) {                 // keep NaN cases
            int idx = atomicAdd(&cntS, 1);
            float* q = lp + idx * 5;
            q[0] = muy; q[1] = mux; q[2] = dy; q[3] = dx; q[4] = p;
        }
    }
    __syncthreads();
    int n = cntS;
    float py = (float)(ty0 + (tid >> 4));
    float px = (float)(tx0 + (tid & 15));
    float m = 0.0f;
    for (int t = 0; t < n; ++t) {
        float muy = lp[t * 5 + 0], mux = lp[t * 5 + 1];
        float dy = lp[t * 5 + 2], dx = lp[t * 5 + 3], p = lp[t * 5 + 4];
        float zy = (py - muy) / dy;
        float zx = (px - mux) / dx;
        float g = expf(-0.5f * (zy * zy + zx * zx)) * p;
        m = fmaxf(m, g);
    }
    heat[(size_t)b * NPIX + (ty0 + (tid >> 4)) * W + tx0 + (tid & 15)] = m;
}

extern "C" void kernel_launch(void* const* d_in, const int* in_sizes, int n_in,
                              void* d_out, int out_size, void* d_ws, size_t ws_size,
                              hipStream_t stream) {
    const float* mask = (const float*)d_in[0];
    const float* bias = (const float*)d_in[1];
    float* out = (float*)d_out;
    char* ws = (char*)d_ws;

    float* score      = (float*)(ws + SCORE_OFF);
    float* fs         = (float*)(ws + FS_OFF);
    int*   fidx       = (int*)(ws + FIDX_OFF);
    int*   Fout       = (int*)(ws + F_OFF);
    int*   cand_idx   = (int*)(ws + CIDX_OFF);
    float* cand_score = (float*)(ws + CSC_OFF);
    float* cand_box   = (float*)(ws + CBOX_OFF);
    u32*   sup        = (u32*)(ws + SUP_OFF);
    u32*   keep       = (u32*)(ws + KEEP_OFF);
    int*   NV         = (int*)(ws + NV_OFF);
    float* params     = (float*)(ws + PAR_OFF);

    // mask passthrough (output 1)
    hipMemcpyAsync(out + OUT_MASK_OFF, mask, (size_t)BATCH * NCH * NPIX * sizeof(float),
                   hipMemcpyDeviceToDevice, stream);

    dim3 g100(NPIX / 256, BATCH);
    k_score<<<g100, 256, 0, stream>>>(mask, score);
    k_compact<<<BATCH, 1024, 0, stream>>>(score, fs, fidx, Fout, cand_idx, cand_score);
    k_rank<<<g100, 256, 0, stream>>>(fs, fidx, Fout, cand_idx, cand_score);
    k_boxes<<<dim3(BATCH * PRE_K / 256), 256, 0, stream>>>(bias, cand_idx, cand_box);
    k_iou<<<dim3(PRE_K / 8, BATCH), 512, 0, stream>>>(cand_box, sup);
    k_nms<<<BATCH, 64, 0, stream>>>(sup, Fout, keep);
    k_finalize<<<BATCH, 256, 0, stream>>>(keep, cand_score, cand_box,
                                          out + OUT_BOX_OFF, out + OUT_VAL_OFF, params, NV);
    k_heat<<<dim3(TPL * (H / TILE), BATCH), 256, 0, stream>>>(params, NV, out + OUT_HEAT_OFF);
}

// Round 5
// 137.700 us; speedup vs baseline: 3.2702x; 1.4023x over previous
//
#include <hip/hip_runtime.h>
#include <math.h>

#define BATCH 4
#define NCH 4
#define H 160
#define W 160
#define NPIX (H * W)          // 25600
#define PRE_K 2048
#define TOPK 500
#define PROB_T 0.75f
#define IOU_T 0.5f
#define COV 10.0f

// ---- workspace layout (bytes) ----
#define SCORE_OFF 0u                 // float [B][NPIX]
#define FS_OFF    409600u            // float [B][NPIX]  frontal scores (raster order)
#define FIDX_OFF  819200u            // int   [B][NPIX]  frontal pixel idx
#define F_OFF     1228800u           // int   [B]
#define CIDX_OFF  1228864u           // int   [B][PRE_K]
#define CSC_OFF   1261632u           // float [B][PRE_K]
#define CBOX_OFF  1294400u           // float [B][PRE_K][4]
#define SUP_OFF   1425472u           // u32   [B][PRE_K][64]  (row-major, coalesced rows)
#define KEEP_OFF  3522624u           // u32   [B][64]
#define NV_OFF    3523648u           // int   [B]
#define PAR_OFF   3523712u           // float [B][TOPK][5]  (muy,mux,dy,dx,p)
#define FLAG_OFF  3563712u           // u8    [B][PRE_K]  row-has-any-suppression flags

// out layout (floats)
#define OUT_HEAT_OFF 0
#define OUT_MASK_OFF 102400
#define OUT_BOX_OFF  512000
#define OUT_VAL_OFF  520000

typedef unsigned long long u64;
typedef unsigned int u32;

// -------- block exclusive scan over 256 ints (used by k_finalize) --------
__device__ __forceinline__ int block_scan_excl(int v, int tid, int* tmp, int* total) {
    tmp[tid] = v;
    __syncthreads();
    for (int off = 1; off < 256; off <<= 1) {
        int y = (tid >= off) ? tmp[tid - off] : 0;
        __syncthreads();
        tmp[tid] += y;
        __syncthreads();
    }
    int incl = tmp[tid];
    *total = tmp[255];
    __syncthreads();
    return incl - v;
}

// K1: per-pixel softmax-max / argmax / score
__global__ void k_score(const float* __restrict__ mask, float* __restrict__ score) {
    int b = blockIdx.y;
    int pix = blockIdx.x * 256 + threadIdx.x;
    const float* mp = mask + (size_t)b * NCH * NPIX + pix;
    float x0 = mp[0], x1 = mp[NPIX], x2 = mp[2 * NPIX], x3 = mp[3 * NPIX];
    float m = x0; int c = 0;
    if (x1 > m) { m = x1; c = 1; }
    if (x2 > m) { m = x2; c = 2; }
    if (x3 > m) { m = x3; c = 3; }
    float sum = ((expf(x0 - m) + expf(x1 - m)) + expf(x2 - m)) + expf(x3 - m);
    float prob = 1.0f / sum;
    bool frontal = (c != 0) && (prob > PROB_T);
    score[(size_t)b * NPIX + pix] = frontal ? prob : -1.0f;
}

// K2: ordered compaction, single pass.
#define PPT (NPIX / 1024)   // 25
__global__ void __launch_bounds__(1024)
k_compact(const float* __restrict__ score, float* __restrict__ fs,
          int* __restrict__ fidx, int* __restrict__ Fout,
          int* __restrict__ cand_idx, float* __restrict__ cand_score) {
    int b = blockIdx.x;
    int tid = threadIdx.x;           // 0..1023
    const float* sc = score + (size_t)b * NPIX;
    int p0 = tid * PPT;
    float v[PPT];
    int cnt = 0;
    #pragma unroll
    for (int j = 0; j < PPT; ++j) {
        v[j] = sc[p0 + j];
        cnt += (v[j] > 0.0f) ? 1 : 0;
    }
    int lane = tid & 63, wv = tid >> 6;
    int incl = cnt;
    for (int off = 1; off < 64; off <<= 1) {
        int y = __shfl_up(incl, off);
        if (lane >= off) incl += y;
    }
    __shared__ int wtot[16];
    __shared__ int wpre[17];
    if (lane == 63) wtot[wv] = incl;
    __syncthreads();
    if (tid == 0) {
        int acc = 0;
        for (int k = 0; k < 16; ++k) { wpre[k] = acc; acc += wtot[k]; }
        wpre[16] = acc;
    }
    __syncthreads();
    int f_excl = wpre[wv] + (incl - cnt);
    int F = wpre[16];
    if (tid == 0) Fout[b] = F;
    int w = f_excl;
    #pragma unroll
    for (int j = 0; j < PPT; ++j) {
        if (v[j] > 0.0f) {
            fs[(size_t)b * NPIX + w] = v[j];
            fidx[(size_t)b * NPIX + w] = p0 + j;
            ++w;
        }
    }
    if (F < PRE_K) {
        int slot = F + (p0 - f_excl);
        if (slot < PRE_K) {
            #pragma unroll
            for (int j = 0; j < PPT; ++j) {
                if (!(v[j] > 0.0f)) {
                    if (slot < PRE_K) {
                        cand_idx[(size_t)b * PRE_K + slot] = p0 + j;
                        cand_score[(size_t)b * PRE_K + slot] = -1.0f;
                    }
                    ++slot;
                }
            }
        }
    }
}

// K3: exact rank of each frontal element (JAX top_k semantics: desc value, ties -> lower idx)
__global__ void k_rank(const float* __restrict__ fs, const int* __restrict__ fidx,
                       const int* __restrict__ Fout, int* __restrict__ cand_idx,
                       float* __restrict__ cand_score) {
    int b = blockIdx.y;
    int F = Fout[b];
    if (blockIdx.x * 256 >= F) return;
    int i = blockIdx.x * 256 + threadIdx.x;
    bool act = i < F;
    float si = 0.0f; int xi = 0;
    if (act) { si = fs[(size_t)b * NPIX + i]; xi = fidx[(size_t)b * NPIX + i]; }
    int rank = 0;
    __shared__ float ls[256];
    __shared__ int li[256];
    for (int base = 0; base < F; base += 256) {
        int j = base + threadIdx.x;
        if (j < F) { ls[threadIdx.x] = fs[(size_t)b * NPIX + j]; li[threadIdx.x] = fidx[(size_t)b * NPIX + j]; }
        __syncthreads();
        int lim = min(256, F - base);
        if (act) {
            for (int k = 0; k < lim; ++k) {
                float sj = ls[k]; int xj = li[k];
                rank += (sj > si || (sj == si && xj < xi)) ? 1 : 0;
            }
        }
        __syncthreads();
    }
    if (act && rank < PRE_K) {
        cand_idx[(size_t)b * PRE_K + rank] = xi;
        cand_score[(size_t)b * PRE_K + rank] = si;
    }
}

// K4: build candidate boxes (y,x,y,x) + bias
__global__ void k_boxes(const float* __restrict__ bias, const int* __restrict__ cand_idx,
                        float* __restrict__ cand_box) {
    int t = blockIdx.x * 256 + threadIdx.x;   // [0, BATCH*PRE_K)
    int b = t >> 11;
    int s = t & (PRE_K - 1);
    int pix = cand_idx[(size_t)b * PRE_K + s];
    float y = (float)(pix / W), x = (float)(pix % W);
    const float* bb = bias + (size_t)b * 4 * NPIX;
    float4 box;
    box.x = y + bb[0 * NPIX + pix];
    box.y = x + bb[1 * NPIX + pix];
    box.z = y + bb[2 * NPIX + pix];
    box.w = x + bb[3 * NPIX + pix];
    ((float4*)cand_box)[(size_t)b * PRE_K + s] = box;
}

// K5: suppression bitmatrix, u32 granularity, row-contiguous. Also emits a
// per-row byte flag = (row has any suppression bit) for k_nms's sparse walk.
__global__ void __launch_bounds__(512)
k_iou(const float* __restrict__ cand_box, u32* __restrict__ sup,
      unsigned char* __restrict__ flag) {
    int b = blockIdx.y;
    int r0 = blockIdx.x * 8;
    __shared__ float ly1[PRE_K], lx1[PRE_K], ly2[PRE_K], lx2[PRE_K], lar[PRE_K];
    for (int k = threadIdx.x; k < PRE_K; k += 512) {
        float4 v = ((const float4*)cand_box)[(size_t)b * PRE_K + k];
        ly1[k] = v.x; lx1[k] = v.y; ly2[k] = v.z; lx2[k] = v.w;
        lar[k] = (v.z - v.x) * (v.w - v.y);
    }
    __syncthreads();
    int lr = threadIdx.x >> 6;      // 0..7 (one wave per row)
    int w = threadIdx.x & 63;       // 0..63 word lane
    int i = r0 + lr;
    float ay1 = ly1[i], ax1 = lx1[i], ay2 = ly2[i], ax2 = lx2[i], aa = lar[i];
    u32 bits = 0;
    int jbase = w * 32;
    #pragma unroll 4
    for (int jj = 0; jj < 32; ++jj) {
        int jo = (jj + w) & 31;             // bank-conflict-free rotation
        int j = jbase + jo;
        if (j > i) {
            float lty = fmaxf(ay1, ly1[j]);
            float ltx = fmaxf(ax1, lx1[j]);
            float rby = fminf(ay2, ly2[j]);
            float rbx = fminf(ax2, lx2[j]);
            float wy = fmaxf(rby - lty, 0.0f);
            float wx = fmaxf(rbx - ltx, 0.0f);
            float inter = wy * wx;
            float iou = inter / ((aa + lar[j]) - inter);
            if (iou > IOU_T) bits |= (1u << jo);
        }
    }
    sup[((size_t)b * PRE_K + i) * 64 + w] = bits;
    bool any = __any(bits != 0u);
    if (w == 0) flag[(size_t)b * PRE_K + i] = any ? 1 : 0;
}

// K6: serial greedy NMS over NONZERO rows only. One wave per image.
// Preamble: wave-scan the 2KB flag array -> ordered list of nonzero rows (LDS).
// Main loop: 4-chunk x 8-row register ring pipeline (32 loads in flight),
// readlane keep-bit check (scalar chain ~15 cyc/row).
__global__ void __launch_bounds__(64)
k_nms(const u32* __restrict__ sup, const unsigned char* __restrict__ flag,
      const int* __restrict__ Fout, u32* __restrict__ keep) {
    int b = blockIdx.x;
    int lane = threadIdx.x;          // 0..63
    int F = Fout[b];
    int V = F < PRE_K ? F : PRE_K;
    __shared__ int rid_s[PRE_K];

    // ---- ordered nonzero-row list ----
    const u32* f32 = (const u32*)(flag + (size_t)b * PRE_K);
    u32 fw[8];
    #pragma unroll
    for (int k = 0; k < 8; ++k) fw[k] = f32[lane * 8 + k];
    int r0 = lane * 32;
    int cnt = 0;
    #pragma unroll
    for (int k = 0; k < 8; ++k) {
        #pragma unroll
        for (int j = 0; j < 4; ++j) {
            int r = r0 + k * 4 + j;
            if (((fw[k] >> (8 * j)) & 0xFFu) != 0u && r < V) ++cnt;
        }
    }
    int incl = cnt;
    for (int off = 1; off < 64; off <<= 1) {
        int y = __shfl_up(incl, off);
        if (lane >= off) incl += y;
    }
    int M = __shfl(incl, 63);
    int pos = incl - cnt;
    #pragma unroll
    for (int k = 0; k < 8; ++k) {
        #pragma unroll
        for (int j = 0; j < 4; ++j) {
            int r = r0 + k * 4 + j;
            if (((fw[k] >> (8 * j)) & 0xFFu) != 0u && r < V) rid_s[pos++] = r;
        }
    }
    __syncthreads();

    int rem = V - lane * 32;
    u32 kw = (rem >= 32) ? 0xFFFFFFFFu : (rem <= 0 ? 0u : ((1u << rem) - 1u));

    const u32* supb = sup + (size_t)b * PRE_K * 64 + lane;  // lane = word index
    int C = (M + 7) >> 3;
    int C4 = (C + 3) & ~3;
    int l7 = lane & 7;

    u32 rbuf[4][8];
    int ridv[4];

    #define LOAD_RID(slot, c) ridv[slot] = rid_s[min((c) * 8 + l7, PRE_K - 1)]
    #define ISSUE(slot) do { \
        _Pragma("unroll") \
        for (int k_ = 0; k_ < 8; ++k_) { \
            int i_ = __builtin_amdgcn_readlane(ridv[slot], k_) & (PRE_K - 1); \
            rbuf[slot][k_] = supb[(size_t)i_ * 64]; \
        } \
    } while (0)
    #define PROC(slot, c) do { \
        _Pragma("unroll") \
        for (int k_ = 0; k_ < 8; ++k_) { \
            int m_ = (c) * 8 + k_; \
            if (m_ < M) { \
                int i_ = __builtin_amdgcn_readlane(ridv[slot], k_) & (PRE_K - 1); \
                u32 kb_ = (u32)__builtin_amdgcn_readlane((int)kw, i_ >> 5); \
                if ((kb_ >> (i_ & 31)) & 1u) kw &= ~rbuf[slot][k_]; \
            } \
        } \
    } while (0)

    // preamble: rid for chunks 0..3, rows for chunks 0..2
    LOAD_RID(0, 0); LOAD_RID(1, 1); LOAD_RID(2, 2); LOAD_RID(3, 3);
    ISSUE(0); ISSUE(1); ISSUE(2);

    for (int c = 0; c < C4; c += 4) {
        PROC(0, c);     ISSUE(3);            LOAD_RID(0, c + 4);
        PROC(1, c + 1); ISSUE(0);            LOAD_RID(1, c + 5);
        PROC(2, c + 2); ISSUE(1);            LOAD_RID(2, c + 6);
        PROC(3, c + 3); ISSUE(2);            LOAD_RID(3, c + 7);
    }
    #undef LOAD_RID
    #undef ISSUE
    #undef PROC

    keep[(size_t)b * 64 + lane] = kw;
}

// K7: final top-500 (kept slots in order, then non-kept in slot order) + outputs + heat params
__global__ void k_finalize(const u32* __restrict__ keep, const float* __restrict__ cand_score,
                           const float* __restrict__ cand_box, float* __restrict__ out_boxes,
                           float* __restrict__ out_valid, float* __restrict__ params,
                           int* __restrict__ NV) {
    int b = blockIdx.x;
    int tid = threadIdx.x;
    __shared__ u32 kws[64];
    __shared__ int tmp[256];
    if (tid < 64) kws[tid] = keep[(size_t)b * 64 + tid];
    __syncthreads();
    int s0 = tid * 8;
    int bits8 = (int)((kws[s0 >> 5] >> (s0 & 31)) & 0xFFu);
    int cnt = __popc(bits8);
    int tot;
    int kpre = block_scan_excl(cnt, tid, tmp, &tot);
    int NK = tot;
    for (int k = 0; k < 8; ++k) {
        int s = s0 + k;
        int kept = (bits8 >> k) & 1;
        int pos = kept ? kpre : (NK + s - kpre);
        if (pos < TOPK) {
            float4 bx = ((const float4*)cand_box)[(size_t)b * PRE_K + s];
            ((float4*)out_boxes)[(size_t)b * TOPK + pos] = bx;
            out_valid[(size_t)b * TOPK + pos] = kept ? 1.0f : 0.0f;
            if (kept) {
                float scv = cand_score[(size_t)b * PRE_K + s];
                float* pp = params + ((size_t)b * TOPK + pos) * 5;
                pp[0] = (bx.x + bx.z) * 0.5f;   // muy
                pp[1] = (bx.y + bx.w) * 0.5f;   // mux
                pp[2] = (bx.z - bx.x) / COV;    // sigma_y / cov
                pp[3] = (bx.w - bx.y) / COV;    // sigma_x / cov
                pp[4] = scv;                    // prob
            }
        }
        kpre += kept;
    }
    if (tid == 0) NV[b] = NK < TOPK ? NK : TOPK;
}

// K8: tiled heat map with per-tile Gaussian culling.
#define TILE 16
#define TPL (W / TILE)   // 10 tiles per row
__global__ void k_heat(const float* __restrict__ params, const int* __restrict__ NV,
                       float* __restrict__ heat) {
    int b = blockIdx.y;
    int ty0 = (blockIdx.x / TPL) * TILE;
    int tx0 = (blockIdx.x % TPL) * TILE;
    int tid = threadIdx.x;
    int nv = NV[b];
    __shared__ float lp[TOPK * 5];
    __shared__ int cntS;
    if (tid == 0) cntS = 0;
    __syncthreads();
    for (int t = tid; t < nv; t += 256) {
        const float* pp = params + ((size_t)b * TOPK + t) * 5;
        float muy = pp[0], mux = pp[1], dy = pp[2], dx = pp[3], p = pp[4];
        float cy = fmaxf(fmaxf((float)ty0 - muy, muy - (float)(ty0 + TILE - 1)), 0.0f);
        float cx = fmaxf(fmaxf((float)tx0 - mux, mux - (float)(tx0 + TILE - 1)), 0.0f);
        float zy = cy / fabsf(dy);
        float zx = cx / fabsf(dx);
        float z2 = zy * zy + zx * zx;
        if (!(z2 > 40.0f)) {                 // keep NaN cases
            int idx = atomicAdd(&cntS, 1);
            float* q = lp + idx * 5;
            q[0] = muy; q[1] = mux; q[2] = dy; q[3] = dx; q[4] = p;
        }
    }
    __syncthreads();
    int n = cntS;
    float py = (float)(ty0 + (tid >> 4));
    float px = (float)(tx0 + (tid & 15));
    float m = 0.0f;
    for (int t = 0; t < n; ++t) {
        float muy = lp[t * 5 + 0], mux = lp[t * 5 + 1];
        float dy = lp[t * 5 + 2], dx = lp[t * 5 + 3], p = lp[t * 5 + 4];
        float zy = (py - muy) / dy;
        float zx = (px - mux) / dx;
        float g = expf(-0.5f * (zy * zy + zx * zx)) * p;
        m = fmaxf(m, g);
    }
    heat[(size_t)b * NPIX + (ty0 + (tid >> 4)) * W + tx0 + (tid & 15)] = m;
}

extern "C" void kernel_launch(void* const* d_in, const int* in_sizes, int n_in,
                              void* d_out, int out_size, void* d_ws, size_t ws_size,
                              hipStream_t stream) {
    const float* mask = (const float*)d_in[0];
    const float* bias = (const float*)d_in[1];
    float* out = (float*)d_out;
    char* ws = (char*)d_ws;

    float* score      = (float*)(ws + SCORE_OFF);
    float* fs         = (float*)(ws + FS_OFF);
    int*   fidx       = (int*)(ws + FIDX_OFF);
    int*   Fout       = (int*)(ws + F_OFF);
    int*   cand_idx   = (int*)(ws + CIDX_OFF);
    float* cand_score = (float*)(ws + CSC_OFF);
    float* cand_box   = (float*)(ws + CBOX_OFF);
    u32*   sup        = (u32*)(ws + SUP_OFF);
    u32*   keep       = (u32*)(ws + KEEP_OFF);
    int*   NV         = (int*)(ws + NV_OFF);
    float* params     = (float*)(ws + PAR_OFF);
    unsigned char* flag = (unsigned char*)(ws + FLAG_OFF);

    // mask passthrough (output 1)
    hipMemcpyAsync(out + OUT_MASK_OFF, mask, (size_t)BATCH * NCH * NPIX * sizeof(float),
                   hipMemcpyDeviceToDevice, stream);

    dim3 g100(NPIX / 256, BATCH);
    k_score<<<g100, 256, 0, stream>>>(mask, score);
    k_compact<<<BATCH, 1024, 0, stream>>>(score, fs, fidx, Fout, cand_idx, cand_score);
    k_rank<<<g100, 256, 0, stream>>>(fs, fidx, Fout, cand_idx, cand_score);
    k_boxes<<<dim3(BATCH * PRE_K / 256), 256, 0, stream>>>(bias, cand_idx, cand_box);
    k_iou<<<dim3(PRE_K / 8, BATCH), 512, 0, stream>>>(cand_box, sup, flag);
    k_nms<<<BATCH, 64, 0, stream>>>(sup, flag, Fout, keep);
    k_finalize<<<BATCH, 256, 0, stream>>>(keep, cand_score, cand_box,
                                          out + OUT_BOX_OFF, out + OUT_VAL_OFF, params, NV);
    k_heat<<<dim3(TPL * (H / TILE), BATCH), 256, 0, stream>>>(params, NV, out + OUT_HEAT_OFF);
}